// Round 24
// baseline (234.948 us; speedup 1.0000x reference)
//
#include <hip/hip_runtime.h>
#include <hip/hip_bf16.h>

typedef unsigned short u16;
typedef unsigned int   u32;
typedef __bf16 bf16x8 __attribute__((ext_vector_type(8)));
typedef float  f32x4  __attribute__((ext_vector_type(4)));
typedef u32    u32x4  __attribute__((ext_vector_type(4)));

#define TRI_TOTAL 131328  // sum_{n=0}^{511} (n+1)

__device__ __forceinline__ float b2f(u16 u) {
    return __builtin_bit_cast(float, ((u32)u) << 16);
}
__device__ __forceinline__ u16 f2b(float f) {
    return __builtin_bit_cast(u16, __float2bfloat16(f));
}
// swizzle (<=2-way on all used phases); offsets < 256 so valid for 256B rows
__device__ __forceinline__ int pcol(int col) {
    return (((col & 7) ^ ((col >> 3) & 7)) << 4);
}
// async global->LDS, 16B per lane, wave-uniform LDS base
__device__ __forceinline__ void gload_lds16(const void* g, void* l) {
    __builtin_amdgcn_global_load_lds(
        (const __attribute__((address_space(1))) void*)g,
        (__attribute__((address_space(3))) void*)l, 16, 0, 0);
}
// (d,m)-packed row offsets
__device__ __forceinline__ u32 qoff(int d) {          // Q/V: rows 512-d per d
    return 512u * (u32)d - (u32)((d * (d - 1)) >> 1);
}
__device__ __forceinline__ u32 koff(int r) {          // K: rows r+1 per r
    return (u32)((r * (r + 1)) >> 1);
}

// ---------------- LayerNorm -> xn (bf16) ----------------
__global__ void __launch_bounds__(256) ln_kernel(const float* __restrict__ x,
                                                 const float* __restrict__ g,
                                                 const float* __restrict__ b,
                                                 u16* __restrict__ xn) {
    int n = blockIdx.x, t = threadIdx.x;
    float v = x[n * 256 + t];
    __shared__ float red[4];
    float s = v;
    #pragma unroll
    for (int o = 32; o >= 1; o >>= 1) s += __shfl_xor(s, o);
    if ((t & 63) == 0) red[t >> 6] = s;
    __syncthreads();
    float mu = (red[0] + red[1] + red[2] + red[3]) * (1.0f / 256.0f);
    float d = v - mu;
    __syncthreads();
    float s2 = d * d;
    #pragma unroll
    for (int o = 32; o >= 1; o >>= 1) s2 += __shfl_xor(s2, o);
    if ((t & 63) == 0) red[t >> 6] = s2;
    __syncthreads();
    float var = (red[0] + red[1] + red[2] + red[3]) * (1.0f / 256.0f);
    float y = d * rsqrtf(var + 1e-5f) * g[t] + b[t];
    xn[n * 256 + t] = f2b(y);
}

// ---------------- Per-relative-index projections (v23) ----------------
// (d,m)-PACKED outputs (contiguous tile writes). 32-row A tiles:
// LDS = 2x16KB A dbuf + 4.5KB obuf = 37376 B -> exactly 4 blocks/CU.
// At 4 blocks/CU the compiler's occupancy ceiling is 4 waves/SIMD (5 blocks
// cannot fit), so the VGPR budget is 128 and the 16 reg-resident B-frags
// survive (v16/v18's 32KB-LDS failure mode is structurally excluded).
// W staged per r in two k-halves through the free 16KB buffer.
__global__ void __launch_bounds__(256) proj_kernel(
        const u16* __restrict__ xn,
        const float* __restrict__ Wq, const float* __restrict__ Wk,
        const float* __restrict__ Wv,
        u16* __restrict__ Qa, u16* __restrict__ Ka, u16* __restrict__ Va) {
    __shared__ char lds[16384 * 2 + 32 * 144];
    char* obuf = lds + 32768;       // 32 x 64 u16 out-tile, pitch 144

    int bid = blockIdx.x;           // 1536 blocks
    int which = bid % 3;            // 0=Q,1=K,2=V
    int rr = bid / 3;               // 0..511
    int strip = rr >> 2;            // 0..127, 4 r's each, heavy-first
    int cs = rr & 3;
    const float* W = (which == 0) ? Wq : ((which == 1) ? Wk : Wv);
    u16* Out       = (which == 0) ? Qa : ((which == 1) ? Ka : Va);

    int t = threadIdx.x;
    int c0 = cs * 64;
    int wv  = t >> 6;               // 0..3
    int rg  = wv >> 1;              // row-group: rows [rg*16, rg*16+16)
    int cg  = wv & 1;               // col-group: cols [cg*32, cg*32+32)
    int L   = t & 63;
    int l15 = L & 15, l4 = L >> 4;
    int c4 = (t & 15) * 4;          // W-stage: 4 consecutive cols
    int kq = t >> 4;                // W-stage: 0..15 -> k = K0 + kq*8 + i

    int r, rows, pbase;
    u32 obase;
#define SET_R(Q) do {                                                         \
    int rq_ = strip * 4 + (Q);                                                \
    r = (which == 1) ? (511 - rq_) : rq_;                                     \
    rows  = (which == 1) ? (r + 1) : (512 - r);                               \
    pbase = (which == 1) ? (511 - r) : 0;                                     \
    obase = (which == 1) ? koff(r) : qoff(r);                                 \
} while (0)

    // ---- async 32-row A-tile DMA: wave wv covers rows [wv*8, wv*8+8) ----
#define DMA_TILE(DST, M0) do {                                                \
    _Pragma("unroll")                                                         \
    for (int j = 0; j < 4; ++j) {                                             \
        int lrow = wv * 8 + 2 * j + (L >> 5);                                 \
        int grow = pbase + (M0) + lrow; if (grow > 511) grow = 511;           \
        const char* gp = (const char*)xn + (size_t)grow * 512                 \
                         + (((L & 31) ^ (lrow & 7)) << 4);                    \
        char* lp = (DST) + (wv * 8 + 2 * j) * 512;                            \
        gload_lds16(gp, lp);                                                  \
    }                                                                         \
} while (0)

    // ---- W half-stage: 64 cols x 128 k (K0=0 or 128) -> 16KB bf16 buffer
    // layout [col][k-K0] (256B rows), pcol-swizzled; 16B packed writes.
#define W_HALF(DST, K0) do {                                                  \
    const float* wp_ = W + ((size_t)r << 16) + c0 + c4                        \
                       + (size_t)((K0) + kq * 8) * 256;                       \
    f32x4 h0 = *(const f32x4*)(wp_ + 0 * 256);                                \
    f32x4 h1 = *(const f32x4*)(wp_ + 1 * 256);                                \
    f32x4 h2 = *(const f32x4*)(wp_ + 2 * 256);                                \
    f32x4 h3 = *(const f32x4*)(wp_ + 3 * 256);                                \
    f32x4 h4 = *(const f32x4*)(wp_ + 4 * 256);                                \
    f32x4 h5 = *(const f32x4*)(wp_ + 5 * 256);                                \
    f32x4 h6 = *(const f32x4*)(wp_ + 6 * 256);                                \
    f32x4 h7 = *(const f32x4*)(wp_ + 7 * 256);                                \
    _Pragma("unroll")                                                         \
    for (int c = 0; c < 4; ++c) {                                             \
        int col = c4 + c;                                                     \
        u32x4 pr;                                                             \
        pr[0] = (u32)f2b(h0[c]) | ((u32)f2b(h1[c]) << 16);                    \
        pr[1] = (u32)f2b(h2[c]) | ((u32)f2b(h3[c]) << 16);                    \
        pr[2] = (u32)f2b(h4[c]) | ((u32)f2b(h5[c]) << 16);                    \
        pr[3] = (u32)f2b(h6[c]) | ((u32)f2b(h7[c]) << 16);                    \
        *(u32x4*)((DST) + col * 256 + ((kq * 16) ^ pcol(col))) = pr;          \
    }                                                                         \
} while (0)

    // ---- B-frag extraction (per half) ----
    bf16x8 b00, b01, b02, b03, b04, b05, b06, b07;
    bf16x8 b10, b11, b12, b13, b14, b15, b16, b17;
    int colA = cg * 32 + l15, colB = cg * 32 + 16 + l15;
    int pA = pcol(colA), pB = pcol(colB);
#define BEXT_H0(SRC) do {                                                     \
    b00 = *(const bf16x8*)((SRC) + colA * 256 + ((0 * 64 + l4 * 16) ^ pA));   \
    b01 = *(const bf16x8*)((SRC) + colA * 256 + ((1 * 64 + l4 * 16) ^ pA));   \
    b02 = *(const bf16x8*)((SRC) + colA * 256 + ((2 * 64 + l4 * 16) ^ pA));   \
    b03 = *(const bf16x8*)((SRC) + colA * 256 + ((3 * 64 + l4 * 16) ^ pA));   \
    b10 = *(const bf16x8*)((SRC) + colB * 256 + ((0 * 64 + l4 * 16) ^ pB));   \
    b11 = *(const bf16x8*)((SRC) + colB * 256 + ((1 * 64 + l4 * 16) ^ pB));   \
    b12 = *(const bf16x8*)((SRC) + colB * 256 + ((2 * 64 + l4 * 16) ^ pB));   \
    b13 = *(const bf16x8*)((SRC) + colB * 256 + ((3 * 64 + l4 * 16) ^ pB));   \
} while (0)
#define BEXT_H1(SRC) do {                                                     \
    b04 = *(const bf16x8*)((SRC) + colA * 256 + ((0 * 64 + l4 * 16) ^ pA));   \
    b05 = *(const bf16x8*)((SRC) + colA * 256 + ((1 * 64 + l4 * 16) ^ pA));   \
    b06 = *(const bf16x8*)((SRC) + colA * 256 + ((2 * 64 + l4 * 16) ^ pA));   \
    b07 = *(const bf16x8*)((SRC) + colA * 256 + ((3 * 64 + l4 * 16) ^ pA));   \
    b14 = *(const bf16x8*)((SRC) + colB * 256 + ((0 * 64 + l4 * 16) ^ pB));   \
    b15 = *(const bf16x8*)((SRC) + colB * 256 + ((1 * 64 + l4 * 16) ^ pB));   \
    b16 = *(const bf16x8*)((SRC) + colB * 256 + ((2 * 64 + l4 * 16) ^ pB));   \
    b17 = *(const bf16x8*)((SRC) + colB * 256 + ((3 * 64 + l4 * 16) ^ pB));   \
} while (0)

    int am = (l15 & 7) << 4;
    char* cur = lds;
    char* alt = lds + 16384;
    int tr2 = t >> 3, sg = t & 7;   // store-stage: row, 16B segment

    for (int q = 0; q < 4; ++q) {
        SET_R(q);
        DMA_TILE(cur, 0);           // A(0) flies under the W staging
        W_HALF(alt, 0);
        __syncthreads();            // half0 writes visible
        BEXT_H0(alt);
        __syncthreads();            // half0 reads done
        W_HALF(alt, 128);
        __syncthreads();            // half1 writes visible
        BEXT_H1(alt);
        asm volatile("s_waitcnt vmcnt(0)" ::: "memory");  // A(0) drained
        __syncthreads();            // half1 reads done; alt free

        int nt = (rows + 31) >> 5;
        for (int i = 0; i < nt; ++i) {
            int m0 = i << 5;
            bool lastt = (i + 1 >= nt);
            if (!lastt) DMA_TILE(alt, m0 + 32);   // 4 vmem, issued FIRST

            const char* abase = cur + (rg * 16 + l15) * 512;
            f32x4 acc0 = {}, acc1 = {};
#define KS(ks) {                                                              \
        int kb = (ks) * 64 + l4 * 16;                                         \
        bf16x8 a0 = *(const bf16x8*)(abase + (kb ^ am));                      \
        acc0 = __builtin_amdgcn_mfma_f32_16x16x32_bf16(a0, b0##ks, acc0, 0, 0, 0); \
        acc1 = __builtin_amdgcn_mfma_f32_16x16x32_bf16(a0, b1##ks, acc1, 0, 0, 0); \
    }
            KS(0) KS(1) KS(2) KS(3) KS(4) KS(5) KS(6) KS(7)
#undef KS
            // bounce acc -> obuf (row-major u16, pitch 144)
            {
                char* ob = obuf + (size_t)(rg * 16) * 144 + (cg * 32 + l15) * 2;
                #pragma unroll
                for (int j = 0; j < 4; ++j) {
                    int rl = l4 * 4 + j;
                    *(u16*)(ob + rl * 144)      = f2b(acc0[j]);
                    *(u16*)(ob + rl * 144 + 32) = f2b(acc1[j]);
                }
            }
            __syncthreads();        // bounce visible
            // coalesced store: thread -> (row tr2, 16B seg sg); rows are
            // CONTIGUOUS in the packed layout
            {
                int ml = m0 + tr2;
                if (ml < rows) {
                    u16* op = Out + (size_t)(obase + (u32)ml) * 256 + c0 + sg * 8;
                    *(u32x4*)op = *(const u32x4*)(obuf + tr2 * 144 + sg * 16);
                }
            }
            if (!lastt) { asm volatile("s_waitcnt vmcnt(1)" ::: "memory"); }
            else        { asm volatile("s_waitcnt vmcnt(0)" ::: "memory"); }
            __builtin_amdgcn_s_barrier();
            __builtin_amdgcn_sched_barrier(0);
            { char* tmp = cur; cur = alt; alt = tmp; }
        }
    }
#undef DMA_TILE
#undef W_HALF
#undef BEXT_H0
#undef BEXT_H1
#undef SET_R
}

// ---------------- per-row attention (packed reads + LDS row tables) -------
__global__ void __launch_bounds__(256) attn_kernel(const u16* __restrict__ Qa,
                                                   const u16* __restrict__ Ka,
                                                   const u16* __restrict__ Va,
                                                   float* __restrict__ ao) {
    int n = 511 - blockIdx.x, t = threadIdx.x;
    __shared__ float pbuf[512 * 9];   // [m][h] padded pitch 9
    __shared__ float linv[8];
    __shared__ u32 qrt[512];
    __shared__ u32 krt[512];
    int band = n + 1;

    for (int m = t; m < band; m += 256) {
        int dd = n - m;
        qrt[m] = qoff(dd) + (u32)m;
        krt[m] = koff(511 - dd) + (u32)m;
    }
    __syncthreads();

    // scores: thread = (m-inner, h)
    int h = t & 7, mi = t >> 3;
    for (int m0 = 0; m0 < band; m0 += 32) {
        int m = m0 + mi;
        float d = -1e30f;
        if (m < band) {
            const char* qp = (const char*)Qa + (size_t)qrt[m] * 512 + h * 64;
            const char* kp = (const char*)Ka + (size_t)krt[m] * 512 + h * 64;
            float acc = 0.f;
            #pragma unroll
            for (int cch = 0; cch < 4; ++cch) {
                u32x4 qv = *reinterpret_cast<const u32x4*>(qp + cch * 16);
                u32x4 kv = *reinterpret_cast<const u32x4*>(kp + cch * 16);
                #pragma unroll
                for (int i = 0; i < 4; ++i) {
                    float ql = __builtin_bit_cast(float, qv[i] << 16);
                    float qh = __builtin_bit_cast(float, qv[i] & 0xffff0000u);
                    float kl = __builtin_bit_cast(float, kv[i] << 16);
                    float kh = __builtin_bit_cast(float, kv[i] & 0xffff0000u);
                    acc += ql * kl + qh * kh;
                }
            }
            d = acc * 0.17677669529663687f;  // 1/sqrt(32)
        }
        pbuf[m * 9 + h] = d;
    }
    __syncthreads();

    int wv = t >> 6, L = t & 63;
    for (int s = 0; s < 2; ++s) {
        int hh = wv + s * 4;
        float mx = -1e30f;
        for (int m = L; m < band; m += 64) mx = fmaxf(mx, pbuf[m * 9 + hh]);
        #pragma unroll
        for (int o = 32; o >= 1; o >>= 1) mx = fmaxf(mx, __shfl_xor(mx, o));
        float sum = 0.f;
        for (int m = L; m < band; m += 64) {
            float p = __expf(pbuf[m * 9 + hh] - mx);
            pbuf[m * 9 + hh] = p;
            sum += p;
        }
        #pragma unroll
        for (int o = 32; o >= 1; o >>= 1) sum += __shfl_xor(sum, o);
        if (L == 0) linv[hh] = 1.0f / sum;
    }
    __syncthreads();

    // PV: thread = output channel; 16-deep unroll, 8 accumulators
    int h2 = t >> 5;
    const char* vb = (const char*)Va + (size_t)t * 2;
    const float* pb = pbuf + h2;
    float a0 = 0, a1 = 0, a2 = 0, a3 = 0, a4 = 0, a5 = 0, a6 = 0, a7 = 0;
    int m = 0;
#define VROW(MM) ((size_t)qrt[MM] * 512)
    for (; m + 16 <= band; m += 16) {
        u16 v0  = *(const u16*)(vb + VROW(m +  0));
        u16 v1  = *(const u16*)(vb + VROW(m +  1));
        u16 v2  = *(const u16*)(vb + VROW(m +  2));
        u16 v3  = *(const u16*)(vb + VROW(m +  3));
        u16 v4  = *(const u16*)(vb + VROW(m +  4));
        u16 v5  = *(const u16*)(vb + VROW(m +  5));
        u16 v6  = *(const u16*)(vb + VROW(m +  6));
        u16 v7  = *(const u16*)(vb + VROW(m +  7));
        u16 v8  = *(const u16*)(vb + VROW(m +  8));
        u16 v9  = *(const u16*)(vb + VROW(m +  9));
        u16 v10 = *(const u16*)(vb + VROW(m + 10));
        u16 v11 = *(const u16*)(vb + VROW(m + 11));
        u16 v12 = *(const u16*)(vb + VROW(m + 12));
        u16 v13 = *(const u16*)(vb + VROW(m + 13));
        u16 v14 = *(const u16*)(vb + VROW(m + 14));
        u16 v15 = *(const u16*)(vb + VROW(m + 15));
        a0 += pb[(m +  0) * 9] * b2f(v0);
        a1 += pb[(m +  1) * 9] * b2f(v1);
        a2 += pb[(m +  2) * 9] * b2f(v2);
        a3 += pb[(m +  3) * 9] * b2f(v3);
        a4 += pb[(m +  4) * 9] * b2f(v4);
        a5 += pb[(m +  5) * 9] * b2f(v5);
        a6 += pb[(m +  6) * 9] * b2f(v6);
        a7 += pb[(m +  7) * 9] * b2f(v7);
        a0 += pb[(m +  8) * 9] * b2f(v8);
        a1 += pb[(m +  9) * 9] * b2f(v9);
        a2 += pb[(m + 10) * 9] * b2f(v10);
        a3 += pb[(m + 11) * 9] * b2f(v11);
        a4 += pb[(m + 12) * 9] * b2f(v12);
        a5 += pb[(m + 13) * 9] * b2f(v13);
        a6 += pb[(m + 14) * 9] * b2f(v14);
        a7 += pb[(m + 15) * 9] * b2f(v15);
    }
    for (; m < band; ++m)
        a0 += pb[m * 9] * b2f(*(const u16*)(vb + VROW(m)));
#undef VROW
    ao[n * 256 + t] = (((a0 + a1) + (a2 + a3)) + ((a4 + a5) + (a6 + a7)))
                      * linv[h2];
}

// ---------------- output projection ----------------
__global__ void __launch_bounds__(256) outproj_kernel(const float* __restrict__ ao,
                                                      const float* __restrict__ Wo,
                                                      const float* __restrict__ bo,
                                                      float* __restrict__ out) {
    int n = blockIdx.x, e = threadIdx.x;
    const float* a = ao + n * 256;
    float c0 = bo[e], c1 = 0, c2 = 0, c3 = 0;
    for (int c = 0; c < 256; c += 4) {
        c0 += a[c + 0] * Wo[(c + 0) * 256 + e];
        c1 += a[c + 1] * Wo[(c + 1) * 256 + e];
        c2 += a[c + 2] * Wo[(c + 2) * 256 + e];
        c3 += a[c + 3] * Wo[(c + 3) * 256 + e];
    }
    out[n * 256 + e] = (c0 + c1) + (c2 + c3);
}

extern "C" void kernel_launch(void* const* d_in, const int* in_sizes, int n_in,
                              void* d_out, int out_size, void* d_ws, size_t ws_size,
                              hipStream_t stream) {
    const float* x     = (const float*)d_in[0];
    const float* Wq    = (const float*)d_in[1];
    const float* Wk    = (const float*)d_in[2];
    const float* Wv    = (const float*)d_in[3];
    const float* gamma = (const float*)d_in[4];
    const float* beta  = (const float*)d_in[5];
    const float* Wo    = (const float*)d_in[6];
    const float* bo    = (const float*)d_in[7];
    float* out = (float*)d_out;

    char* ws = (char*)d_ws;
    u16* xn = (u16*)ws;
    size_t off = (size_t)512 * 256 * 2;
    u16* Qa = (u16*)(ws + off); off += (size_t)TRI_TOTAL * 256 * 2;
    u16* Ka = (u16*)(ws + off); off += (size_t)TRI_TOTAL * 256 * 2;
    u16* Va = (u16*)(ws + off); off += (size_t)TRI_TOTAL * 256 * 2;
    float* ao = (float*)(ws + off);

    ln_kernel<<<512, 256, 0, stream>>>(x, gamma, beta, xn);
    proj_kernel<<<1536, 256, 0, stream>>>(xn, Wq, Wk, Wv, Qa, Ka, Va);
    attn_kernel<<<512, 256, 0, stream>>>(Qa, Ka, Va, ao);
    outproj_kernel<<<512, 256, 0, stream>>>(ao, Wo, bo, out);
}

// Round 25
// 227.333 us; speedup vs baseline: 1.0335x; 1.0335x over previous
//
#include <hip/hip_runtime.h>
#include <hip/hip_bf16.h>

typedef unsigned short u16;
typedef unsigned int   u32;
typedef __bf16 bf16x8 __attribute__((ext_vector_type(8)));
typedef float  f32x4  __attribute__((ext_vector_type(4)));
typedef u32    u32x4  __attribute__((ext_vector_type(4)));
typedef u32    u32x2  __attribute__((ext_vector_type(2)));

#define TRI_TOTAL 131328  // sum_{n=0}^{511} (n+1)

__device__ __forceinline__ float b2f(u16 u) {
    return __builtin_bit_cast(float, ((u32)u) << 16);
}
__device__ __forceinline__ u16 f2b(float f) {
    return __builtin_bit_cast(u16, __float2bfloat16(f));
}
// Wl swizzle: <=2-way (free) for k-fast reads and col-fast writes
__device__ __forceinline__ int pcol(int col) {
    return (((col & 7) ^ ((col >> 3) & 7)) << 4);
}
// async global->LDS, 16B per lane, wave-uniform LDS base
__device__ __forceinline__ void gload_lds16(const void* g, void* l) {
    __builtin_amdgcn_global_load_lds(
        (const __attribute__((address_space(1))) void*)g,
        (__attribute__((address_space(3))) void*)l, 16, 0, 0);
}
// (d,m)-packed row offsets
__device__ __forceinline__ u32 qoff(int d) {          // Q/V: rows 512-d per d
    return 512u * (u32)d - (u32)((d * (d - 1)) >> 1);
}
__device__ __forceinline__ u32 koff(int r) {          // K: rows r+1 per r
    return (u32)((r * (r + 1)) >> 1);
}

// ---------------- LayerNorm -> xn (bf16) ----------------
__global__ void __launch_bounds__(256) ln_kernel(const float* __restrict__ x,
                                                 const float* __restrict__ g,
                                                 const float* __restrict__ b,
                                                 u16* __restrict__ xn) {
    int n = blockIdx.x, t = threadIdx.x;
    float v = x[n * 256 + t];
    __shared__ float red[4];
    float s = v;
    #pragma unroll
    for (int o = 32; o >= 1; o >>= 1) s += __shfl_xor(s, o);
    if ((t & 63) == 0) red[t >> 6] = s;
    __syncthreads();
    float mu = (red[0] + red[1] + red[2] + red[3]) * (1.0f / 256.0f);
    float d = v - mu;
    __syncthreads();
    float s2 = d * d;
    #pragma unroll
    for (int o = 32; o >= 1; o >>= 1) s2 += __shfl_xor(s2, o);
    if ((t & 63) == 0) red[t >> 6] = s2;
    __syncthreads();
    float var = (red[0] + red[1] + red[2] + red[3]) * (1.0f / 256.0f);
    float y = d * rsqrtf(var + 1e-5f) * g[t] + b[t];
    xn[n * 256 + t] = f2b(y);
}

// ---------------- Per-relative-index projections (v21, best measured) -----
// (d,m)-PACKED layout: Q/V block r writes rows qoff(r)+ml (CONTIGUOUS),
// K block r writes rows koff(r)+ml (CONTIGUOUS).
__global__ void __launch_bounds__(256) proj_kernel(
        const u16* __restrict__ xn,
        const float* __restrict__ Wq, const float* __restrict__ Wk,
        const float* __restrict__ Wv,
        u16* __restrict__ Qa, u16* __restrict__ Ka, u16* __restrict__ Va) {
    __shared__ char lds[65536 + 64 * 144];
    char* bufA = lds;            // Wl first, then joins A rotation
    char* bufB = lds + 32768;
    char* obuf = lds + 65536;    // 64 x 64 u16 out-tile, pitch 144

    int bid = blockIdx.x;           // 1536 blocks
    int which = bid % 3;            // 0=Q,1=K,2=V
    int rr = bid / 3;               // 0..511
    int strip = rr >> 2;            // 0..127, 4 r's each, heavy-first
    int cs = rr & 3;
    const float* W = (which == 0) ? Wq : ((which == 1) ? Wk : Wv);
    u16* Out       = (which == 0) ? Qa : ((which == 1) ? Ka : Va);

    int t = threadIdx.x;
    int c0 = cs * 64;
    int wv  = t >> 6;               // 0..3
    int rg  = wv >> 1;              // row-group
    int cg  = wv & 1;               // col-group
    int L   = t & 63;
    int l15 = L & 15, l4 = L >> 4;
    int c4 = (t & 15) * 4;          // W-stage: 4 consecutive cols
    int kq = t >> 4;                // W-stage: k-quad index

    int r, rows, pbase;
    u32 obase;
#define SET_R(Q) do {                                                         \
    int rq_ = strip * 4 + (Q);                                                \
    r = (which == 1) ? (511 - rq_) : rq_;                                     \
    rows  = (which == 1) ? (r + 1) : (512 - r);                               \
    pbase = (which == 1) ? (511 - r) : 0;                                     \
    obase = (which == 1) ? koff(r) : qoff(r);                                 \
} while (0)
    SET_R(0);

#define DMA_TILE(DST, M0) do {                                                \
    _Pragma("unroll")                                                         \
    for (int j = 0; j < 8; ++j) {                                             \
        int lrow = wv * 16 + 2 * j + (L >> 5);                                \
        int grow = pbase + (M0) + lrow; if (grow > 511) grow = 511;           \
        const char* gp = (const char*)xn + (size_t)grow * 512                 \
                         + (((L & 31) ^ (lrow & 7)) << 4);                    \
        char* lp = (DST) + (wv * 16 + 2 * j) * 512;                           \
        gload_lds16(gp, lp);                                                  \
    }                                                                         \
} while (0)

#define DMA_WHALF(DST, R) do {                                                \
    const char* wsrc = (const char*)(W + ((size_t)(R) << 16) + c0);           \
    _Pragma("unroll")                                                         \
    for (int p = 0; p < 8; ++p) {                                             \
        int kk = p * 16 + (t >> 4);                                           \
        const char* gp = wsrc + (size_t)kk * 1024 + (t & 15) * 16;            \
        char* lp = (DST) + p * 4096 + (t >> 6) * 1024;                        \
        gload_lds16(gp, lp);                                                  \
    }                                                                         \
} while (0)

#define WLW(DST, IT, VA, VB, VC, VD) {                                        \
        int kbase2 = (kq * 4 + (IT) * 64) * 2;                                \
        _Pragma("unroll")                                                     \
        for (int i = 0; i < 4; ++i) {                                         \
            int col = c4 + i;                                                 \
            u32 lo = (u32)f2b(VA[i]) | ((u32)f2b(VB[i]) << 16);               \
            u32 hi = (u32)f2b(VC[i]) | ((u32)f2b(VD[i]) << 16);               \
            u32x2 pr; pr[0] = lo; pr[1] = hi;                                 \
            *(u32x2*)((DST) + col * 512 + (kbase2 ^ pcol(col))) = pr;         \
        }                                                                     \
    }

    DMA_TILE(bufB, 0);              // A(0) for r0 flies under the W stage

    // ---- full W stage for r0 -> bufA ----
    {
        const float* wp = W + ((size_t)r << 16) + c0 + c4 + (size_t)(kq * 4) * 256;
        f32x4 w00 = *(const f32x4*)(wp + 0);
        f32x4 w01 = *(const f32x4*)(wp + 256);
        f32x4 w02 = *(const f32x4*)(wp + 512);
        f32x4 w03 = *(const f32x4*)(wp + 768);
        f32x4 w10 = *(const f32x4*)(wp + 16384 + 0);
        f32x4 w11 = *(const f32x4*)(wp + 16384 + 256);
        f32x4 w12 = *(const f32x4*)(wp + 16384 + 512);
        f32x4 w13 = *(const f32x4*)(wp + 16384 + 768);
        f32x4 w20 = *(const f32x4*)(wp + 32768 + 0);
        f32x4 w21 = *(const f32x4*)(wp + 32768 + 256);
        f32x4 w22 = *(const f32x4*)(wp + 32768 + 512);
        f32x4 w23 = *(const f32x4*)(wp + 32768 + 768);
        f32x4 w30 = *(const f32x4*)(wp + 49152 + 0);
        f32x4 w31 = *(const f32x4*)(wp + 49152 + 256);
        f32x4 w32 = *(const f32x4*)(wp + 49152 + 512);
        f32x4 w33 = *(const f32x4*)(wp + 49152 + 768);
        WLW(bufA, 0, w00, w01, w02, w03)
        WLW(bufA, 1, w10, w11, w12, w13)
        WLW(bufA, 2, w20, w21, w22, w23)
        WLW(bufA, 3, w30, w31, w32, w33)
    }
    __syncthreads();                // Wl ready; tile-0 DMA drained

    // ---- B-frag extraction ----
    bf16x8 b00, b01, b02, b03, b04, b05, b06, b07;
    bf16x8 b10, b11, b12, b13, b14, b15, b16, b17;
#define BEXT(SRC) do {                                                        \
    int colA_ = cg * 32 + l15, colB_ = cg * 32 + 16 + l15;                    \
    b00 = *(const bf16x8*)((SRC) + colA_ * 512 + ((0*64 + l4*16) ^ pcol(colA_))); \
    b01 = *(const bf16x8*)((SRC) + colA_ * 512 + ((1*64 + l4*16) ^ pcol(colA_))); \
    b02 = *(const bf16x8*)((SRC) + colA_ * 512 + ((2*64 + l4*16) ^ pcol(colA_))); \
    b03 = *(const bf16x8*)((SRC) + colA_ * 512 + ((3*64 + l4*16) ^ pcol(colA_))); \
    b04 = *(const bf16x8*)((SRC) + colA_ * 512 + ((4*64 + l4*16) ^ pcol(colA_))); \
    b05 = *(const bf16x8*)((SRC) + colA_ * 512 + ((5*64 + l4*16) ^ pcol(colA_))); \
    b06 = *(const bf16x8*)((SRC) + colA_ * 512 + ((6*64 + l4*16) ^ pcol(colA_))); \
    b07 = *(const bf16x8*)((SRC) + colA_ * 512 + ((7*64 + l4*16) ^ pcol(colA_))); \
    b10 = *(const bf16x8*)((SRC) + colB_ * 512 + ((0*64 + l4*16) ^ pcol(colB_))); \
    b11 = *(const bf16x8*)((SRC) + colB_ * 512 + ((1*64 + l4*16) ^ pcol(colB_))); \
    b12 = *(const bf16x8*)((SRC) + colB_ * 512 + ((2*64 + l4*16) ^ pcol(colB_))); \
    b13 = *(const bf16x8*)((SRC) + colB_ * 512 + ((3*64 + l4*16) ^ pcol(colB_))); \
    b14 = *(const bf16x8*)((SRC) + colB_ * 512 + ((4*64 + l4*16) ^ pcol(colB_))); \
    b15 = *(const bf16x8*)((SRC) + colB_ * 512 + ((5*64 + l4*16) ^ pcol(colB_))); \
    b16 = *(const bf16x8*)((SRC) + colB_ * 512 + ((6*64 + l4*16) ^ pcol(colB_))); \
    b17 = *(const bf16x8*)((SRC) + colB_ * 512 + ((7*64 + l4*16) ^ pcol(colB_))); \
} while (0)
    BEXT(bufA);
    __syncthreads();                // bufA reusable as A

    int am = (l15 & 7) << 4;
    char* cur = bufB;
    char* alt = bufA;
    int tr = t >> 2, qd = t & 3;    // store-stage mapping

    for (int q = 0;;) {
        int rnext = 0;
        if (q < 3) { int rq_ = strip * 4 + q + 1;
                     rnext = (which == 1) ? (511 - rq_) : rq_; }
        int nt = (rows + 63) >> 6;
        for (int i = 0; i < nt; ++i) {
            int m0 = i << 6;
            bool lastt = (i + 1 >= nt);
            if (!lastt)          DMA_TILE(alt, m0 + 64);
            else if (q < 3)      DMA_WHALF(alt, rnext);

            const char* abase = cur + (rg * 32 + l15) * 512;
            f32x4 acc00 = {}, acc01 = {}, acc10 = {}, acc11 = {};
#define KS(ks) {                                                              \
        int kb = (ks) * 64 + l4 * 16;                                         \
        bf16x8 a0 = *(const bf16x8*)(abase + (kb ^ am));                      \
        bf16x8 a1 = *(const bf16x8*)(abase + 16 * 512 + (kb ^ am));           \
        acc00 = __builtin_amdgcn_mfma_f32_16x16x32_bf16(a0, b0##ks, acc00, 0, 0, 0); \
        acc01 = __builtin_amdgcn_mfma_f32_16x16x32_bf16(a0, b1##ks, acc01, 0, 0, 0); \
        acc10 = __builtin_amdgcn_mfma_f32_16x16x32_bf16(a1, b0##ks, acc10, 0, 0, 0); \
        acc11 = __builtin_amdgcn_mfma_f32_16x16x32_bf16(a1, b1##ks, acc11, 0, 0, 0); \
    }
            KS(0) KS(1) KS(2) KS(3) KS(4) KS(5) KS(6) KS(7)
#undef KS
            // bounce acc -> obuf (row-major u16, pitch 144)
            {
                char* ob = obuf + (size_t)(rg * 32) * 144 + (cg * 32 + l15) * 2;
                #pragma unroll
                for (int rf = 0; rf < 2; ++rf) {
                    f32x4 va = rf ? acc10 : acc00;
                    f32x4 vb = rf ? acc11 : acc01;
                    #pragma unroll
                    for (int j = 0; j < 4; ++j) {
                        int rl = rf * 16 + l4 * 4 + j;
                        *(u16*)(ob + rl * 144)      = f2b(va[j]);
                        *(u16*)(ob + rl * 144 + 32) = f2b(vb[j]);
                    }
                }
            }
            __syncthreads();        // bounce visible to all waves
            // coalesced store: 64 consecutive packed rows per tile
            {
                int ml = m0 + tr;
                if (ml < rows) {
                    u16* op = Out + (size_t)(obase + (u32)ml) * 256 + c0 + qd * 16;
                    const char* lb = obuf + tr * 144 + qd * 32;
                    u32x4 o0 = *(const u32x4*)(lb);
                    u32x4 o1 = *(const u32x4*)(lb + 16);
                    *(u32x4*)op = o0;
                    *(u32x4*)(op + 8) = o1;
                }
            }
            if (!lastt) { asm volatile("s_waitcnt vmcnt(2)" ::: "memory"); }
            else        { asm volatile("s_waitcnt vmcnt(0)" ::: "memory"); }
            __builtin_amdgcn_s_barrier();
            __builtin_amdgcn_sched_barrier(0);
            { char* tmp = cur; cur = alt; alt = tmp; }
        }
        if (++q > 3) break;
        // ---- r boundary: cur holds W-half fp32; alt is free ----
        SET_R(q);
        DMA_TILE(alt, 0);           // A(0) for new r (oldest vmem)
        const float* wpg = W + ((size_t)r << 16) + c0 + c4;
        f32x4 gw0 = *(const f32x4*)(wpg + 32768 + (size_t)(kq * 4 + 0) * 256);
        f32x4 gw1 = *(const f32x4*)(wpg + 32768 + (size_t)(kq * 4 + 1) * 256);
        f32x4 gw2 = *(const f32x4*)(wpg + 32768 + (size_t)(kq * 4 + 2) * 256);
        f32x4 gw3 = *(const f32x4*)(wpg + 32768 + (size_t)(kq * 4 + 3) * 256);
        f32x4 gw4 = *(const f32x4*)(wpg + 49152 + (size_t)(kq * 4 + 0) * 256);
        f32x4 gw5 = *(const f32x4*)(wpg + 49152 + (size_t)(kq * 4 + 1) * 256);
        f32x4 gw6 = *(const f32x4*)(wpg + 49152 + (size_t)(kq * 4 + 2) * 256);
        f32x4 gw7 = *(const f32x4*)(wpg + 49152 + (size_t)(kq * 4 + 3) * 256);
        f32x4 lw0 = *(const f32x4*)(cur + (kq * 4 + 0) * 256 + (t & 15) * 16);
        f32x4 lw1 = *(const f32x4*)(cur + (kq * 4 + 1) * 256 + (t & 15) * 16);
        f32x4 lw2 = *(const f32x4*)(cur + (kq * 4 + 2) * 256 + (t & 15) * 16);
        f32x4 lw3 = *(const f32x4*)(cur + (kq * 4 + 3) * 256 + (t & 15) * 16);
        f32x4 lw4 = *(const f32x4*)(cur + (64 + kq * 4 + 0) * 256 + (t & 15) * 16);
        f32x4 lw5 = *(const f32x4*)(cur + (64 + kq * 4 + 1) * 256 + (t & 15) * 16);
        f32x4 lw6 = *(const f32x4*)(cur + (64 + kq * 4 + 2) * 256 + (t & 15) * 16);
        f32x4 lw7 = *(const f32x4*)(cur + (64 + kq * 4 + 3) * 256 + (t & 15) * 16);
        __syncthreads();            // all fp32 reads done before overwrite
        WLW(cur, 0, lw0, lw1, lw2, lw3)
        WLW(cur, 1, lw4, lw5, lw6, lw7)
        WLW(cur, 2, gw0, gw1, gw2, gw3)
        WLW(cur, 3, gw4, gw5, gw6, gw7)
        asm volatile("s_waitcnt vmcnt(0)" ::: "memory");  // A(0) DMA drained
        __syncthreads();
        BEXT(cur);
        __syncthreads();
        { char* tmp = cur; cur = alt; alt = tmp; }  // cur=A(0), alt=free
    }
#undef DMA_TILE
#undef DMA_WHALF
#undef WLW
#undef BEXT
#undef SET_R
}

// ---------------- per-row attention (packed reads + LDS row tables) -------
__global__ void __launch_bounds__(256) attn_kernel(const u16* __restrict__ Qa,
                                                   const u16* __restrict__ Ka,
                                                   const u16* __restrict__ Va,
                                                   float* __restrict__ ao) {
    int n = 511 - blockIdx.x, t = threadIdx.x;
    __shared__ float pbuf[512 * 9];   // [m][h] padded pitch 9
    __shared__ float linv[8];
    __shared__ u32 qrt[512];
    __shared__ u32 krt[512];
    int band = n + 1;

    for (int m = t; m < band; m += 256) {
        int dd = n - m;
        qrt[m] = qoff(dd) + (u32)m;
        krt[m] = koff(511 - dd) + (u32)m;
    }
    __syncthreads();

    // scores: thread = (m-inner, h)
    int h = t & 7, mi = t >> 3;
    for (int m0 = 0; m0 < band; m0 += 32) {
        int m = m0 + mi;
        float d = -1e30f;
        if (m < band) {
            const char* qp = (const char*)Qa + (size_t)qrt[m] * 512 + h * 64;
            const char* kp = (const char*)Ka + (size_t)krt[m] * 512 + h * 64;
            float acc = 0.f;
            #pragma unroll
            for (int cch = 0; cch < 4; ++cch) {
                u32x4 qv = *reinterpret_cast<const u32x4*>(qp + cch * 16);
                u32x4 kv = *reinterpret_cast<const u32x4*>(kp + cch * 16);
                #pragma unroll
                for (int i = 0; i < 4; ++i) {
                    float ql = __builtin_bit_cast(float, qv[i] << 16);
                    float qh = __builtin_bit_cast(float, qv[i] & 0xffff0000u);
                    float kl = __builtin_bit_cast(float, kv[i] << 16);
                    float kh = __builtin_bit_cast(float, kv[i] & 0xffff0000u);
                    acc += ql * kl + qh * kh;
                }
            }
            d = acc * 0.17677669529663687f;  // 1/sqrt(32)
        }
        pbuf[m * 9 + h] = d;
    }
    __syncthreads();

    int wv = t >> 6, L = t & 63;
    for (int s = 0; s < 2; ++s) {
        int hh = wv + s * 4;
        float mx = -1e30f;
        for (int m = L; m < band; m += 64) mx = fmaxf(mx, pbuf[m * 9 + hh]);
        #pragma unroll
        for (int o = 32; o >= 1; o >>= 1) mx = fmaxf(mx, __shfl_xor(mx, o));
        float sum = 0.f;
        for (int m = L; m < band; m += 64) {
            float p = __expf(pbuf[m * 9 + hh] - mx);
            pbuf[m * 9 + hh] = p;
            sum += p;
        }
        #pragma unroll
        for (int o = 32; o >= 1; o >>= 1) sum += __shfl_xor(sum, o);
        if (L == 0) linv[hh] = 1.0f / sum;
    }
    __syncthreads();

    // PV: thread = output channel; 16-deep unroll, 8 accumulators
    int h2 = t >> 5;
    const char* vb = (const char*)Va + (size_t)t * 2;
    const float* pb = pbuf + h2;
    float a0 = 0, a1 = 0, a2 = 0, a3 = 0, a4 = 0, a5 = 0, a6 = 0, a7 = 0;
    int m = 0;
#define VROW(MM) ((size_t)qrt[MM] * 512)
    for (; m + 16 <= band; m += 16) {
        u16 v0  = *(const u16*)(vb + VROW(m +  0));
        u16 v1  = *(const u16*)(vb + VROW(m +  1));
        u16 v2  = *(const u16*)(vb + VROW(m +  2));
        u16 v3  = *(const u16*)(vb + VROW(m +  3));
        u16 v4  = *(const u16*)(vb + VROW(m +  4));
        u16 v5  = *(const u16*)(vb + VROW(m +  5));
        u16 v6  = *(const u16*)(vb + VROW(m +  6));
        u16 v7  = *(const u16*)(vb + VROW(m +  7));
        u16 v8  = *(const u16*)(vb + VROW(m +  8));
        u16 v9  = *(const u16*)(vb + VROW(m +  9));
        u16 v10 = *(const u16*)(vb + VROW(m + 10));
        u16 v11 = *(const u16*)(vb + VROW(m + 11));
        u16 v12 = *(const u16*)(vb + VROW(m + 12));
        u16 v13 = *(const u16*)(vb + VROW(m + 13));
        u16 v14 = *(const u16*)(vb + VROW(m + 14));
        u16 v15 = *(const u16*)(vb + VROW(m + 15));
        a0 += pb[(m +  0) * 9] * b2f(v0);
        a1 += pb[(m +  1) * 9] * b2f(v1);
        a2 += pb[(m +  2) * 9] * b2f(v2);
        a3 += pb[(m +  3) * 9] * b2f(v3);
        a4 += pb[(m +  4) * 9] * b2f(v4);
        a5 += pb[(m +  5) * 9] * b2f(v5);
        a6 += pb[(m +  6) * 9] * b2f(v6);
        a7 += pb[(m +  7) * 9] * b2f(v7);
        a0 += pb[(m +  8) * 9] * b2f(v8);
        a1 += pb[(m +  9) * 9] * b2f(v9);
        a2 += pb[(m + 10) * 9] * b2f(v10);
        a3 += pb[(m + 11) * 9] * b2f(v11);
        a4 += pb[(m + 12) * 9] * b2f(v12);
        a5 += pb[(m + 13) * 9] * b2f(v13);
        a6 += pb[(m + 14) * 9] * b2f(v14);
        a7 += pb[(m + 15) * 9] * b2f(v15);
    }
    for (; m < band; ++m)
        a0 += pb[m * 9] * b2f(*(const u16*)(vb + VROW(m)));
#undef VROW
    ao[n * 256 + t] = (((a0 + a1) + (a2 + a3)) + ((a4 + a5) + (a6 + a7)))
                      * linv[h2];
}

// ---------------- output projection ----------------
__global__ void __launch_bounds__(256) outproj_kernel(const float* __restrict__ ao,
                                                      const float* __restrict__ Wo,
                                                      const float* __restrict__ bo,
                                                      float* __restrict__ out) {
    int n = blockIdx.x, e = threadIdx.x;
    const float* a = ao + n * 256;
    float c0 = bo[e], c1 = 0, c2 = 0, c3 = 0;
    for (int c = 0; c < 256; c += 4) {
        c0 += a[c + 0] * Wo[(c + 0) * 256 + e];
        c1 += a[c + 1] * Wo[(c + 1) * 256 + e];
        c2 += a[c + 2] * Wo[(c + 2) * 256 + e];
        c3 += a[c + 3] * Wo[(c + 3) * 256 + e];
    }
    out[n * 256 + e] = (c0 + c1) + (c2 + c3);
}

extern "C" void kernel_launch(void* const* d_in, const int* in_sizes, int n_in,
                              void* d_out, int out_size, void* d_ws, size_t ws_size,
                              hipStream_t stream) {
    const float* x     = (const float*)d_in[0];
    const float* Wq    = (const float*)d_in[1];
    const float* Wk    = (const float*)d_in[2];
    const float* Wv    = (const float*)d_in[3];
    const float* gamma = (const float*)d_in[4];
    const float* beta  = (const float*)d_in[5];
    const float* Wo    = (const float*)d_in[6];
    const float* bo    = (const float*)d_in[7];
    float* out = (float*)d_out;

    char* ws = (char*)d_ws;
    u16* xn = (u16*)ws;
    size_t off = (size_t)512 * 256 * 2;
    u16* Qa = (u16*)(ws + off); off += (size_t)TRI_TOTAL * 256 * 2;
    u16* Ka = (u16*)(ws + off); off += (size_t)TRI_TOTAL * 256 * 2;
    u16* Va = (u16*)(ws + off); off += (size_t)TRI_TOTAL * 256 * 2;
    float* ao = (float*)(ws + off);

    ln_kernel<<<512, 256, 0, stream>>>(x, gamma, beta, xn);
    proj_kernel<<<1536, 256, 0, stream>>>(xn, Wq, Wk, Wv, Qa, Ka, Va);
    attn_kernel<<<512, 256, 0, stream>>>(Qa, Ka, Va, ao);
    outproj_kernel<<<512, 256, 0, stream>>>(ao, Wo, bo, out);
}